// Round 4
// baseline (5010.496 us; speedup 1.0000x reference)
//
#include <hip/hip_runtime.h>

#define TT 512
#define BB 64
#define II 512
#define HH 1024
#define NBLK 256
#define NTHR 512
#define FSTRIDE 128   // u32 stride between flag sets (512B per set)

typedef short bf16x8 __attribute__((ext_vector_type(8)));
typedef float f32x4 __attribute__((ext_vector_type(4)));
typedef int   i32x4 __attribute__((ext_vector_type(4)));

struct Params {
  const unsigned short* xb;   // [TT][BB][II] bf16
  unsigned short* h0;         // [4][BB][HH] bf16 ring
  unsigned short* h1;         // [4][BB][HH] bf16 ring
  unsigned int* flags;        // [4][FSTRIDE]: per-producer completed-phase counts
                              // set 0/1 = L0 mh0/mh1, set 2/3 = L1 mh0/mh1
  const float* wih0; const float* whh0; const float* bih0; const float* bhh0;
  const float* wih1; const float* whh1; const float* bih1; const float* bhh1;
  float* out;
};

__device__ __forceinline__ unsigned short f2bf(float f) {
  unsigned int u = __float_as_uint(f);
  u += 0x7fffu + ((u >> 16) & 1u);   // round-to-nearest-even
  return (unsigned short)(u >> 16);
}

// coherence-point (bypass L1+L2) accesses — cross-XCD coherent without fences
__device__ __forceinline__ bf16x8 ld_bypass(const unsigned short* p) {
  i32x4 r;
  asm volatile("global_load_dwordx4 %0, %1, off sc0 sc1" : "=v"(r) : "v"(p));
  return __builtin_bit_cast(bf16x8, r);
}
__device__ __forceinline__ void st_bypass_b128(unsigned short* p, i32x4 v) {
  asm volatile("global_store_dwordx4 %0, %1, off sc0 sc1" :: "v"(p), "v"(v) : "memory");
}
__device__ __forceinline__ void st_bypass_u32(unsigned int* p, unsigned int v) {
  asm volatile("global_store_dword %0, %1, off sc0 sc1" :: "v"(p), "v"(v) : "memory");
}

// each lane polls one producer word until it reaches tgt (completed-phase count)
__device__ __forceinline__ void poll_set(const unsigned int* f, int lane, unsigned int tgt) {
  while (__hip_atomic_load(&f[lane], __ATOMIC_RELAXED, __HIP_MEMORY_SCOPE_AGENT) < tgt)
    __builtin_amdgcn_s_sleep(4);
}

__global__ void cvt_kernel(const float* __restrict__ x, unsigned short* __restrict__ xb, int n8) {
  int i = blockIdx.x * blockDim.x + threadIdx.x;
  int stride = gridDim.x * blockDim.x;
  for (; i < n8; i += stride) {
    const float4* p = (const float4*)(x) + (size_t)i * 2;
    float4 a = p[0], b = p[1];
    bf16x8 v;
    v[0] = (short)f2bf(a.x); v[1] = (short)f2bf(a.y); v[2] = (short)f2bf(a.z); v[3] = (short)f2bf(a.w);
    v[4] = (short)f2bf(b.x); v[5] = (short)f2bf(b.y); v[6] = (short)f2bf(b.z); v[7] = (short)f2bf(b.w);
    ((bf16x8*)xb)[i] = v;
  }
}

template <int LAYER>
__device__ void body(const Params& P, float (*pbuf)[64][36], float (*cb)[16],
                     unsigned short (*hbuf)[16]) {
  constexpr int K   = (LAYER == 0) ? (II + HH) : (2 * HH);   // 1536 / 2048
  constexpr int KSL = K / (8 * 32);                          // k-steps per wave: 6 / 8
  constexpr int NG  = KSL / 2;                               // load groups: 3 / 4
  constexpr int KIH = (LAYER == 0) ? II : HH;

  const int tid  = threadIdx.x;
  const int lane = tid & 63;
  const int kh   = tid >> 6;          // wave id = k-eighth
  const int lbid = blockIdx.x & 127;
  const int mh   = lbid >> 6;         // batch half (32 rows)
  const int ns   = lbid & 63;         // 16 hidden units: [ns*16, ns*16+16)
  const int l15  = lane & 15;
  const int lk8  = (lane >> 4) * 8;

  const int setL0 = mh;               // producer sets
  const int setL1 = 2 + mh;
  const int fset  = LAYER * 2 + mh;   // my arrival set

  const float* wih = (LAYER == 0) ? P.wih0 : P.wih1;
  const float* whh = (LAYER == 0) ? P.whh0 : P.whh1;

  // ---- weight B-fragments in registers/AGPRs for the whole kernel ----
  bf16x8 wf[4][KSL];
  #pragma unroll
  for (int nt = 0; nt < 4; ++nt) {          // gate index (i,f,g,o)
    const int row = nt * HH + ns * 16 + l15;
    #pragma unroll
    for (int ks = 0; ks < KSL; ++ks) {
      int k = kh * (KSL * 32) + ks * 32 + lk8;
      const float* src = (k < KIH) ? (wih + (size_t)row * KIH + k)
                                   : (whh + (size_t)row * HH + (k - KIH));
      const float4* p4 = (const float4*)src;
      float4 a = p4[0], b = p4[1];
      bf16x8 v;
      v[0] = (short)f2bf(a.x); v[1] = (short)f2bf(a.y); v[2] = (short)f2bf(a.z); v[3] = (short)f2bf(a.w);
      v[4] = (short)f2bf(b.x); v[5] = (short)f2bf(b.y); v[6] = (short)f2bf(b.z); v[7] = (short)f2bf(b.w);
      wf[nt][ks] = v;
    }
  }

  // ---- per-thread bias (update threads tid<128) ----
  float bv[4];
  {
    const float* bi = (LAYER == 0) ? P.bih0 : P.bih1;
    const float* bh = (LAYER == 0) ? P.bhh0 : P.bhh1;
    int unit = ns * 16 + (tid & 15);
    #pragma unroll
    for (int g = 0; g < 4; ++g) bv[g] = bi[g * HH + unit] + bh[g * HH + unit];
  }

  if (tid < 128) {
    int q = tid >> 4, j = tid & 15;
    #pragma unroll
    for (int r = 0; r < 4; ++r) cb[q * 4 + r][j] = 0.f;
  }

  const size_t BH  = (size_t)BB * HH;
  const size_t TBH = (size_t)TT * BH;

  #pragma unroll 1
  for (int p = 0; p <= TT; ++p) {
    const int t = (LAYER == 0) ? p : p - 1;
    const bool active = (LAYER == 0) ? (p < TT) : (p >= 1);

    // ---- dependency waits (per-producer flags; sets of 64) ----
    if (kh == 0 && p >= 1) {
      // both layers consume L0(mh) phase p-1 output
      poll_set(P.flags + (size_t)setL0 * FSTRIDE, lane, (unsigned)p);
    }
    if (kh == 1) {
      if (LAYER == 0) {
        // anti-overrun: h0 ring is 4 deep; L0 may lead slowest L1 by <=2 phases
        if (p >= 3) poll_set(P.flags + (size_t)setL1 * FSTRIDE, lane, (unsigned)(p - 2));
      } else {
        if (p >= 1) poll_set(P.flags + (size_t)setL1 * FSTRIDE, lane, (unsigned)p);
      }
    }
    __syncthreads();

    f32x4 acc[2][4];
    float hv[4];
    if (active) {
      #pragma unroll
      for (int mt = 0; mt < 2; ++mt)
        #pragma unroll
        for (int nt = 0; nt < 4; ++nt) acc[mt][nt] = f32x4{0.f, 0.f, 0.f, 0.f};

      const unsigned short* h0prev = P.h0 + (size_t)((t - 1) & 3) * BH;
      const unsigned short* h0cur  = P.h0 + (size_t)(t & 3) * BH;
      const unsigned short* h1prev = P.h1 + (size_t)((t - 1) & 3) * BH;

      bf16x8 af[2][2][2];    // [pingpong][ksb][mt]

      auto issue_group = [&](int g, int pp) {
        #pragma unroll
        for (int ksb = 0; ksb < 2; ++ksb) {
          const int ks = g * 2 + ksb;
          const int k  = kh * (KSL * 32) + ks * 32 + lk8;
          #pragma unroll
          for (int mt = 0; mt < 2; ++mt) {
            const int m = mh * 32 + mt * 16 + l15;
            const unsigned short* src;
            if (LAYER == 0) {
              src = (k < II) ? (P.xb + ((size_t)t * BB + m) * II + k)
                             : (h0prev + (size_t)m * HH + (k - II));
            } else {
              src = (k < HH) ? (h0cur + (size_t)m * HH + k)
                             : (h1prev + (size_t)m * HH + (k - HH));
            }
            af[pp][ksb][mt] = ld_bypass(src);
          }
        }
      };

      issue_group(0, 0);
      issue_group(1, 1);
      #pragma unroll
      for (int g = 0; g < NG; ++g) {
        if (g < NG - 1) asm volatile("s_waitcnt vmcnt(4)" ::: "memory");
        else            asm volatile("s_waitcnt vmcnt(0)" ::: "memory");
        __builtin_amdgcn_sched_barrier(0);
        #pragma unroll
        for (int ksb = 0; ksb < 2; ++ksb) {
          const int ks = g * 2 + ksb;
          #pragma unroll
          for (int mt = 0; mt < 2; ++mt)
            #pragma unroll
            for (int nt = 0; nt < 4; ++nt)
              acc[mt][nt] = __builtin_amdgcn_mfma_f32_16x16x32_bf16(af[g & 1][ksb][mt], wf[nt][ks], acc[mt][nt], 0, 0, 0);
        }
        if (g + 2 < NG) issue_group(g + 2, g & 1);
      }

      // stage A: waves 4..7 write partials
      if (kh >= 4) {
        #pragma unroll
        for (int mt = 0; mt < 2; ++mt)
          #pragma unroll
          for (int nt = 0; nt < 4; ++nt) {
            int col = nt * 16 + l15;
            int mb  = mt * 16 + (lane >> 4) * 4;
            *(f32x4*)&pbuf[kh - 4][col][mb] = acc[mt][nt];
          }
      }
    }
    __syncthreads();
    if (active && kh < 4) {
      #pragma unroll
      for (int mt = 0; mt < 2; ++mt)
        #pragma unroll
        for (int nt = 0; nt < 4; ++nt) {
          int col = nt * 16 + l15;
          int mb  = mt * 16 + (lane >> 4) * 4;
          f32x4 v = *(const f32x4*)&pbuf[kh][col][mb];
          acc[mt][nt] += v;
          *(f32x4*)&pbuf[kh][col][mb] = acc[mt][nt];
        }
    }
    __syncthreads();
    // cell update: 128 threads, each owns (m-quad q, unit j)
    if (active && tid < 128) {
      int q = tid >> 4, j = tid & 15;
      f32x4 gv[4];
      #pragma unroll
      for (int g = 0; g < 4; ++g) {
        int col = g * 16 + j;
        f32x4 s = *(const f32x4*)&pbuf[0][col][q * 4];
        #pragma unroll
        for (int w = 1; w < 4; ++w) s += *(const f32x4*)&pbuf[w][col][q * 4];
        gv[g] = s;
      }
      #pragma unroll
      for (int r = 0; r < 4; ++r) {
        int m = q * 4 + r;
        float iv = 1.f / (1.f + __expf(-(gv[0][r] + bv[0])));
        float fv = 1.f / (1.f + __expf(-(gv[1][r] + bv[1])));
        float gg = tanhf(gv[2][r] + bv[2]);
        float ov = 1.f / (1.f + __expf(-(gv[3][r] + bv[3])));
        float c = fv * cb[m][j] + iv * gg;
        cb[m][j] = c;
        float h = ov * tanhf(c);
        hv[r] = h;
        hbuf[m][j] = f2bf(h);
      }
    }
    __syncthreads();
    // publish h (wave 0: 64 coalesced 16B bypass stores), drain, then flag
    if (tid < 64) {
      if (active) {
        int row  = tid >> 1;
        int half = tid & 1;
        i32x4 v = *(const i32x4*)&hbuf[row][half * 8];
        unsigned short* dst = ((LAYER == 0) ? P.h0 : P.h1) +
            (size_t)(t & 3) * BH + (size_t)(mh * 32 + row) * HH + ns * 16 + half * 8;
        st_bypass_b128(dst, v);
      }
      asm volatile("s_waitcnt vmcnt(0)" ::: "memory");
      if (tid == 0)
        st_bypass_u32(P.flags + (size_t)fset * FSTRIDE + ns, (unsigned)(p + 1));
    }
    // out-writes overlap next phase's poll (nobody consumes them)
    if (active && tid < 128) {
      int q = tid >> 4, j = tid & 15;
      #pragma unroll
      for (int r = 0; r < 4; ++r) {
        int mg = mh * 32 + q * 4 + r;
        int unit = ns * 16 + j;
        if (LAYER == 0) {
          if (t == TT - 1) P.out[TBH + (size_t)mg * HH + unit] = hv[r];
        } else {
          P.out[(size_t)t * BH + (size_t)mg * HH + unit] = hv[r];
          if (t == TT - 1) P.out[TBH + BH + (size_t)mg * HH + unit] = hv[r];
        }
      }
    }
    // no trailing barrier: next iteration's poll + __syncthreads is the join
  }

  // final cell state c_f
  if (tid < 128) {
    int q = tid >> 4, j = tid & 15;
    #pragma unroll
    for (int r = 0; r < 4; ++r) {
      int m = q * 4 + r;
      int mg = mh * 32 + m;
      int unit = ns * 16 + j;
      P.out[TBH + (size_t)(2 + LAYER) * BH + (size_t)mg * HH + unit] = cb[m][j];
    }
  }
}

__global__ void __launch_bounds__(NTHR, 1) lstm_kernel(Params P) {
  __shared__ float pbuf[4][64][36];
  __shared__ float cb[32][16];
  __shared__ unsigned short hbuf[32][16];
  if (blockIdx.x < 128) body<0>(P, pbuf, cb, hbuf);
  else                  body<1>(P, pbuf, cb, hbuf);
}

extern "C" void kernel_launch(void* const* d_in, const int* in_sizes, int n_in,
                              void* d_out, int out_size, void* d_ws, size_t ws_size,
                              hipStream_t stream) {
  const float* x = (const float*)d_in[0];
  Params P;
  P.wih0 = (const float*)d_in[1];
  P.whh0 = (const float*)d_in[2];
  P.bih0 = (const float*)d_in[3];
  P.bhh0 = (const float*)d_in[4];
  P.wih1 = (const float*)d_in[5];
  P.whh1 = (const float*)d_in[6];
  P.bih1 = (const float*)d_in[7];
  P.bhh1 = (const float*)d_in[8];
  P.out  = (float*)d_out;

  char* ws = (char*)d_ws;
  P.flags = (unsigned int*)ws;                             // 4 sets * 512B, pad to 8KB
  P.xb  = (const unsigned short*)(ws + 8192);
  unsigned short* xb_w = (unsigned short*)(ws + 8192);
  P.h0  = (unsigned short*)(ws + 8192 + (size_t)TT * BB * II * 2);
  P.h1  = P.h0 + (size_t)4 * BB * HH;

  hipMemsetAsync((void*)P.flags, 0, 8192, stream);
  hipMemsetAsync((void*)P.h0, 0, (size_t)8 * BB * HH * sizeof(unsigned short), stream);

  int n8 = TT * BB * II / 8;
  cvt_kernel<<<2048, 256, 0, stream>>>(x, xb_w, n8);

  void* args[] = { &P };
  hipLaunchCooperativeKernel((void*)lstm_kernel, dim3(NBLK), dim3(NTHR), args, 0, stream);
}

// Round 6
// 3844.017 us; speedup vs baseline: 1.3035x; 1.3035x over previous
//
#include <hip/hip_runtime.h>

#define TT 512
#define BB 64
#define II 512
#define HH 1024
#define NBLK 256
#define NTHR 512
#define FSTRIDE 32    // u32 stride between producer flag words = 128B line each
#define SETSTRIDE (64 * FSTRIDE)   // one set = 64 producers

typedef short bf16x8 __attribute__((ext_vector_type(8)));
typedef float f32x4 __attribute__((ext_vector_type(4)));
typedef int   i32x4 __attribute__((ext_vector_type(4)));

struct Params {
  const unsigned short* xb;   // [TT][BB][II] bf16
  unsigned short* h0;         // [4][BB][HH] bf16 ring
  unsigned short* h1;         // [4][BB][HH] bf16 ring
  unsigned int* flags;        // [4][64][FSTRIDE]: per-producer completed-phase counts
                              // set 0/1 = L0 mh0/mh1, set 2/3 = L1 mh0/mh1
  const float* wih0; const float* whh0; const float* bih0; const float* bhh0;
  const float* wih1; const float* whh1; const float* bih1; const float* bhh1;
  float* out;
};

__device__ __forceinline__ unsigned short f2bf(float f) {
  unsigned int u = __float_as_uint(f);
  u += 0x7fffu + ((u >> 16) & 1u);   // round-to-nearest-even
  return (unsigned short)(u >> 16);
}

// coherence-point (bypass L1+L2) accesses — cross-XCD coherent without fences
__device__ __forceinline__ bf16x8 ld_bypass(const unsigned short* p) {
  i32x4 r;
  asm volatile("global_load_dwordx4 %0, %1, off sc0 sc1" : "=v"(r) : "v"(p));
  return __builtin_bit_cast(bf16x8, r);
}
__device__ __forceinline__ void st_bypass_b128(unsigned short* p, i32x4 v) {
  asm volatile("global_store_dwordx4 %0, %1, off sc0 sc1" :: "v"(p), "v"(v) : "memory");
}
__device__ __forceinline__ void st_bypass_u32(unsigned int* p, unsigned int v) {
  asm volatile("global_store_dword %0, %1, off sc0 sc1" :: "v"(p), "v"(v) : "memory");
}
// THE FIX (round 4 theory, untested due to compile error): flag reads must
// bypass L2 (CP read). A relaxed agent-scope atomic load can be lowered as an
// L2-hitting load, so the poller spins on a stale local-XCD L2 line until
// chance eviction — multi-us nondeterministic detect latency.
__device__ __forceinline__ unsigned int ld_flag_bypass(const unsigned int* p) {
  unsigned int r;
  asm volatile("global_load_dword %0, %1, off sc0 sc1\n\t"
               "s_waitcnt vmcnt(0)" : "=v"(r) : "v"(p) : "memory");
  return r;
}

// each lane polls one producer word until it reaches tgt (SLP must be literal)
template <int SLP>
__device__ __forceinline__ void poll_set(const unsigned int* f, int lane,
                                         unsigned int tgt) {
  while (ld_flag_bypass(&f[lane * FSTRIDE]) < tgt)
    __builtin_amdgcn_s_sleep(SLP);
}

__global__ void cvt_kernel(const float* __restrict__ x, unsigned short* __restrict__ xb, int n8) {
  int i = blockIdx.x * blockDim.x + threadIdx.x;
  int stride = gridDim.x * blockDim.x;
  for (; i < n8; i += stride) {
    const float4* p = (const float4*)(x) + (size_t)i * 2;
    float4 a = p[0], b = p[1];
    bf16x8 v;
    v[0] = (short)f2bf(a.x); v[1] = (short)f2bf(a.y); v[2] = (short)f2bf(a.z); v[3] = (short)f2bf(a.w);
    v[4] = (short)f2bf(b.x); v[5] = (short)f2bf(b.y); v[6] = (short)f2bf(b.z); v[7] = (short)f2bf(b.w);
    ((bf16x8*)xb)[i] = v;
  }
}

template <int LAYER>
__device__ void body(const Params& P, float (*pbuf)[64][36], float (*cb)[16],
                     unsigned short (*hbuf)[16]) {
  constexpr int K   = (LAYER == 0) ? (II + HH) : (2 * HH);   // 1536 / 2048
  constexpr int KSL = K / (8 * 32);                          // k-steps per wave: 6 / 8
  constexpr int NG  = KSL / 2;                               // load groups: 3 / 4
  constexpr int KIH = (LAYER == 0) ? II : HH;

  const int tid  = threadIdx.x;
  const int lane = tid & 63;
  const int kh   = tid >> 6;          // wave id = k-eighth
  const int lbid = blockIdx.x & 127;
  const int mh   = lbid >> 6;         // batch half (32 rows)
  const int ns   = lbid & 63;         // 16 hidden units: [ns*16, ns*16+16)
  const int l15  = lane & 15;
  const int lk8  = (lane >> 4) * 8;

  const int setL0 = mh;               // producer sets
  const int setL1 = 2 + mh;
  const int fset  = LAYER * 2 + mh;   // my arrival set

  const float* wih = (LAYER == 0) ? P.wih0 : P.wih1;
  const float* whh = (LAYER == 0) ? P.whh0 : P.whh1;

  // ---- weight B-fragments in registers/AGPRs for the whole kernel ----
  bf16x8 wf[4][KSL];
  #pragma unroll
  for (int nt = 0; nt < 4; ++nt) {          // gate index (i,f,g,o)
    const int row = nt * HH + ns * 16 + l15;
    #pragma unroll
    for (int ks = 0; ks < KSL; ++ks) {
      int k = kh * (KSL * 32) + ks * 32 + lk8;
      const float* src = (k < KIH) ? (wih + (size_t)row * KIH + k)
                                   : (whh + (size_t)row * HH + (k - KIH));
      const float4* p4 = (const float4*)src;
      float4 a = p4[0], b = p4[1];
      bf16x8 v;
      v[0] = (short)f2bf(a.x); v[1] = (short)f2bf(a.y); v[2] = (short)f2bf(a.z); v[3] = (short)f2bf(a.w);
      v[4] = (short)f2bf(b.x); v[5] = (short)f2bf(b.y); v[6] = (short)f2bf(b.z); v[7] = (short)f2bf(b.w);
      wf[nt][ks] = v;
    }
  }

  // ---- per-thread bias (update threads tid<128) ----
  float bv[4];
  {
    const float* bi = (LAYER == 0) ? P.bih0 : P.bih1;
    const float* bh = (LAYER == 0) ? P.bhh0 : P.bhh1;
    int unit = ns * 16 + (tid & 15);
    #pragma unroll
    for (int g = 0; g < 4; ++g) bv[g] = bi[g * HH + unit] + bh[g * HH + unit];
  }

  if (tid < 128) {
    int q = tid >> 4, j = tid & 15;
    #pragma unroll
    for (int r = 0; r < 4; ++r) cb[q * 4 + r][j] = 0.f;
  }

  const size_t BH  = (size_t)BB * HH;
  const size_t TBH = (size_t)TT * BH;

  #pragma unroll 1
  for (int p = 0; p <= TT; ++p) {
    const int t = (LAYER == 0) ? p : p - 1;
    const bool active = (LAYER == 0) ? (p < TT) : (p >= 1);

    // ---- dependency waits (per-producer flags; sets of 64) ----
    if (kh == 0 && p >= 1) {
      // both layers consume L0(mh) phase p-1 output
      poll_set<1>(P.flags + (size_t)setL0 * SETSTRIDE, lane, (unsigned)p);
    }
    if (kh == 1) {
      if (LAYER == 0) {
        // anti-overrun: h0 ring is 4 deep; L0 may lead slowest L1 by <=2 phases.
        // L0 has >=1 full phase of slack here — poll lazily (big sleep).
        if (p >= 3) poll_set<8>(P.flags + (size_t)setL1 * SETSTRIDE, lane, (unsigned)(p - 2));
      } else {
        if (p >= 1) poll_set<1>(P.flags + (size_t)setL1 * SETSTRIDE, lane, (unsigned)p);
      }
    }
    __syncthreads();

    f32x4 acc[2][4];
    float hv[4];
    if (active) {
      #pragma unroll
      for (int mt = 0; mt < 2; ++mt)
        #pragma unroll
        for (int nt = 0; nt < 4; ++nt) acc[mt][nt] = f32x4{0.f, 0.f, 0.f, 0.f};

      const unsigned short* h0prev = P.h0 + (size_t)((t - 1) & 3) * BH;
      const unsigned short* h0cur  = P.h0 + (size_t)(t & 3) * BH;
      const unsigned short* h1prev = P.h1 + (size_t)((t - 1) & 3) * BH;

      bf16x8 af[2][2][2];    // [pingpong][ksb][mt]

      auto issue_group = [&](int g, int pp) {
        #pragma unroll
        for (int ksb = 0; ksb < 2; ++ksb) {
          const int ks = g * 2 + ksb;
          const int k  = kh * (KSL * 32) + ks * 32 + lk8;
          #pragma unroll
          for (int mt = 0; mt < 2; ++mt) {
            const int m = mh * 32 + mt * 16 + l15;
            const unsigned short* src;
            if (LAYER == 0) {
              src = (k < II) ? (P.xb + ((size_t)t * BB + m) * II + k)
                             : (h0prev + (size_t)m * HH + (k - II));
            } else {
              src = (k < HH) ? (h0cur + (size_t)m * HH + k)
                             : (h1prev + (size_t)m * HH + (k - HH));
            }
            af[pp][ksb][mt] = ld_bypass(src);
          }
        }
      };

      issue_group(0, 0);
      issue_group(1, 1);
      #pragma unroll
      for (int g = 0; g < NG; ++g) {
        if (g < NG - 1) asm volatile("s_waitcnt vmcnt(4)" ::: "memory");
        else            asm volatile("s_waitcnt vmcnt(0)" ::: "memory");
        __builtin_amdgcn_sched_barrier(0);
        #pragma unroll
        for (int ksb = 0; ksb < 2; ++ksb) {
          const int ks = g * 2 + ksb;
          #pragma unroll
          for (int mt = 0; mt < 2; ++mt)
            #pragma unroll
            for (int nt = 0; nt < 4; ++nt)
              acc[mt][nt] = __builtin_amdgcn_mfma_f32_16x16x32_bf16(af[g & 1][ksb][mt], wf[nt][ks], acc[mt][nt], 0, 0, 0);
        }
        if (g + 2 < NG) issue_group(g + 2, g & 1);
      }

      // stage A: waves 4..7 write partials
      if (kh >= 4) {
        #pragma unroll
        for (int mt = 0; mt < 2; ++mt)
          #pragma unroll
          for (int nt = 0; nt < 4; ++nt) {
            int col = nt * 16 + l15;
            int mb  = mt * 16 + (lane >> 4) * 4;
            *(f32x4*)&pbuf[kh - 4][col][mb] = acc[mt][nt];
          }
      }
    }
    __syncthreads();
    if (active && kh < 4) {
      #pragma unroll
      for (int mt = 0; mt < 2; ++mt)
        #pragma unroll
        for (int nt = 0; nt < 4; ++nt) {
          int col = nt * 16 + l15;
          int mb  = mt * 16 + (lane >> 4) * 4;
          f32x4 v = *(const f32x4*)&pbuf[kh][col][mb];
          acc[mt][nt] += v;
          *(f32x4*)&pbuf[kh][col][mb] = acc[mt][nt];
        }
    }
    __syncthreads();
    // cell update: 128 threads, each owns (m-quad q, unit j)
    if (active && tid < 128) {
      int q = tid >> 4, j = tid & 15;
      f32x4 gv[4];
      #pragma unroll
      for (int g = 0; g < 4; ++g) {
        int col = g * 16 + j;
        f32x4 s = *(const f32x4*)&pbuf[0][col][q * 4];
        #pragma unroll
        for (int w = 1; w < 4; ++w) s += *(const f32x4*)&pbuf[w][col][q * 4];
        gv[g] = s;
      }
      #pragma unroll
      for (int r = 0; r < 4; ++r) {
        int m = q * 4 + r;
        float iv = 1.f / (1.f + __expf(-(gv[0][r] + bv[0])));
        float fv = 1.f / (1.f + __expf(-(gv[1][r] + bv[1])));
        float gg = tanhf(gv[2][r] + bv[2]);
        float ov = 1.f / (1.f + __expf(-(gv[3][r] + bv[3])));
        float c = fv * cb[m][j] + iv * gg;
        cb[m][j] = c;
        float h = ov * tanhf(c);
        hv[r] = h;
        hbuf[m][j] = f2bf(h);
      }
    }
    __syncthreads();
    // publish h (wave 0: 64 coalesced 16B bypass stores), drain, then flag
    if (tid < 64) {
      if (active) {
        int row  = tid >> 1;
        int half = tid & 1;
        i32x4 v = *(const i32x4*)&hbuf[row][half * 8];
        unsigned short* dst = ((LAYER == 0) ? P.h0 : P.h1) +
            (size_t)(t & 3) * BH + (size_t)(mh * 32 + row) * HH + ns * 16 + half * 8;
        st_bypass_b128(dst, v);
      }
      asm volatile("s_waitcnt vmcnt(0)" ::: "memory");
      if (tid == 0)
        st_bypass_u32(P.flags + (size_t)fset * SETSTRIDE + (size_t)ns * FSTRIDE,
                      (unsigned)(p + 1));
    }
    // out-writes overlap next phase's poll (nobody consumes them)
    if (active && tid < 128) {
      int q = tid >> 4, j = tid & 15;
      #pragma unroll
      for (int r = 0; r < 4; ++r) {
        int mg = mh * 32 + q * 4 + r;
        int unit = ns * 16 + j;
        if (LAYER == 0) {
          if (t == TT - 1) P.out[TBH + (size_t)mg * HH + unit] = hv[r];
        } else {
          P.out[(size_t)t * BH + (size_t)mg * HH + unit] = hv[r];
          if (t == TT - 1) P.out[TBH + BH + (size_t)mg * HH + unit] = hv[r];
        }
      }
    }
    // no trailing barrier: next iteration's poll + __syncthreads is the join
  }

  // final cell state c_f
  if (tid < 128) {
    int q = tid >> 4, j = tid & 15;
    #pragma unroll
    for (int r = 0; r < 4; ++r) {
      int m = q * 4 + r;
      int mg = mh * 32 + m;
      int unit = ns * 16 + j;
      P.out[TBH + (size_t)(2 + LAYER) * BH + (size_t)mg * HH + unit] = cb[m][j];
    }
  }
}

__global__ void __launch_bounds__(NTHR, 1) lstm_kernel(Params P) {
  __shared__ float pbuf[4][64][36];
  __shared__ float cb[32][16];
  __shared__ unsigned short hbuf[32][16];
  if (blockIdx.x < 128) body<0>(P, pbuf, cb, hbuf);
  else                  body<1>(P, pbuf, cb, hbuf);
}

extern "C" void kernel_launch(void* const* d_in, const int* in_sizes, int n_in,
                              void* d_out, int out_size, void* d_ws, size_t ws_size,
                              hipStream_t stream) {
  const float* x = (const float*)d_in[0];
  Params P;
  P.wih0 = (const float*)d_in[1];
  P.whh0 = (const float*)d_in[2];
  P.bih0 = (const float*)d_in[3];
  P.bhh0 = (const float*)d_in[4];
  P.wih1 = (const float*)d_in[5];
  P.whh1 = (const float*)d_in[6];
  P.bih1 = (const float*)d_in[7];
  P.bhh1 = (const float*)d_in[8];
  P.out  = (float*)d_out;

  char* ws = (char*)d_ws;
  P.flags = (unsigned int*)ws;                             // 4 sets * 64 * 128B = 32KB
  P.xb  = (const unsigned short*)(ws + 32768);
  unsigned short* xb_w = (unsigned short*)(ws + 32768);
  P.h0  = (unsigned short*)(ws + 32768 + (size_t)TT * BB * II * 2);
  P.h1  = P.h0 + (size_t)4 * BB * HH;

  (void)hipMemsetAsync((void*)P.flags, 0, 32768, stream);
  (void)hipMemsetAsync((void*)P.h0, 0, (size_t)8 * BB * HH * sizeof(unsigned short), stream);

  int n8 = TT * BB * II / 8;
  cvt_kernel<<<2048, 256, 0, stream>>>(x, xb_w, n8);

  void* args[] = { &P };
  (void)hipLaunchCooperativeKernel((void*)lstm_kernel, dim3(NBLK), dim3(NTHR), args, 0, stream);
}